// Round 20
// baseline (8439.330 us; speedup 1.0000x reference)
//
#include <hip/hip_runtime.h>
#include <stdint.h>

#define T_STEPS 256
#define BATCH   8192

// Reference semantics (proven, round-16 P0 + rounds 17/19 pass, absmax=0):
//   cur  = sum_k fmaf(w[k], s_k, acc) ascending, single acc; + bias at end
//   mem' = fmaf(0.95, mem, cur) - reset    (reset from OLD mem, {0,1})
//   spike = mem' > 1.0
__device__ __forceinline__ float lif_update(float mem, float cur) {
#pragma clang fp contract(off)
    float reset = (mem > 1.0f) ? 1.0f : 0.0f;
    return fmaf(0.95f, mem, cur) - reset;
}

// wave-uniform mask bit -> float {0.0,1.0} (lowers to SALU extract + v_cvt)
__device__ __forceinline__ float ubit(uint32_t mask, int k) {
    return (float)((mask >> k) & 1u);
}

#define F2_STRIDE 76   // odd dword-stride (19 dword-quads) -> bank-spread b128

__global__ __launch_bounds__(256, 3)
void snn_kernel(const float* __restrict__ left, const float* __restrict__ right,
                const float* __restrict__ ctx,
                const float* __restrict__ Wl1, const float* __restrict__ bl1,
                const float* __restrict__ Wl2, const float* __restrict__ bl2,
                const float* __restrict__ Wr1, const float* __restrict__ br1,
                const float* __restrict__ Wr2, const float* __restrict__ br2,
                const float* __restrict__ Wc,  const float* __restrict__ bc,
                const float* __restrict__ Wf,  const float* __restrict__ bf,
                const float* __restrict__ Wf2, const float* __restrict__ bf2,
                const float* __restrict__ Wo,  const float* __restrict__ bo,
                float* __restrict__ out)
{
    const int lane = threadIdx.x & 63;
    const int b    = blockIdx.x * 4 + (threadIdx.x >> 6);

    const int j32 = lane & 31;
    const int jc  = lane & 15;
    const int jf2 = (lane < 48) ? lane : 47;  // lanes 48-63 shadow, excluded from ballot
    const int n_o = lane >> 4;

    // ---- LDS: f2 weights [48 rows x 64, stride 76] + Wo [4x48] ----
    __shared__ __align__(16) float wf2_s[48 * F2_STRIDE];
    __shared__ __align__(16) float wo_s[4 * 48];
    for (int i = threadIdx.x; i < 48 * 64; i += 256) {
        const int r = i >> 6, c = i & 63;
        wf2_s[r * F2_STRIDE + c] = Wf2[i];
    }
    for (int i = threadIdx.x; i < 4 * 48; i += 256) wo_s[i] = Wo[i];
    __syncthreads();
    const float4* wf2q = reinterpret_cast<const float4*>(&wf2_s[jf2 * F2_STRIDE]);
    const float4* wo4  = reinterpret_cast<const float4*>(&wo_s[n_o * 48]);

    // ---- register weights: 6+32+3+80 = 121 floats/lane ----
    float w1[6], w2[32], wcr[3], wf[80];
    const float* W1row = (lane < 32) ? (Wl1 + lane * 6)  : (Wr1 + j32 * 6);
    const float* W2row = (lane < 32) ? (Wl2 + lane * 32) : (Wr2 + j32 * 32);
    const float  b1    = (lane < 32) ? bl1[lane] : br1[j32];
    const float  b2    = (lane < 32) ? bl2[lane] : br2[j32];
#pragma unroll
    for (int k = 0; k < 6;  ++k) w1[k]  = W1row[k];
#pragma unroll
    for (int k = 0; k < 32; ++k) w2[k]  = W2row[k];
#pragma unroll
    for (int k = 0; k < 3;  ++k) wcr[k] = Wc[jc * 3 + k];
    const float bcr = bc[jc];
#pragma unroll
    for (int k = 0; k < 80; ++k) wf[k]  = Wf[lane * 80 + k];
    const float bfr = bf[lane];
    const float bf2r = bf2[jf2];
    const float bor = bo[n_o];

    // ---- membrane state ----
    float ml1 = 0.f, ml2 = 0.f, mc = 0.f, mf = 0.f, mf2 = 0.f, mo = 0.f;

    for (int t = 0; t < T_STEPS; ++t) {
        const size_t base = (size_t)t * BATCH + b;

        // ---- inputs -> one ballot ----
        float vin = 0.f;
        if (lane < 6)                     vin = left [base * 6 + lane];
        else if (lane >= 32 && lane < 38) vin = right[base * 6 + (lane - 32)];
        else if (lane >= 8 && lane < 11)  vin = ctx  [base * 3 + (lane - 8)];
        const uint64_t in_mask = __ballot(vin > 0.5f);
        const uint32_t inLo = (uint32_t)in_mask;
        const uint32_t inHi = (uint32_t)(in_mask >> 32);

        // ---- l1/r1: dual uniform accumulation, per-lane select ----
        {
            float aLo = 0.f, aHi = 0.f;
#pragma unroll
            for (int k = 0; k < 6; ++k) {
                aLo = fmaf(w1[k], ubit(inLo, k), aLo);
                aHi = fmaf(w1[k], ubit(inHi, k), aHi);
            }
            const float acc = (lane < 32) ? aLo : aHi;
            ml1 = lif_update(ml1, acc + b1);
        }
        const uint64_t s1 = __ballot(ml1 > 1.0f);
        const uint32_t s1Lo = (uint32_t)s1, s1Hi = (uint32_t)(s1 >> 32);

        // ---- l2/r2 ----
        {
            float aLo = 0.f, aHi = 0.f;
#pragma unroll
            for (int k = 0; k < 32; ++k) {
                aLo = fmaf(w2[k], ubit(s1Lo, k), aLo);
                aHi = fmaf(w2[k], ubit(s1Hi, k), aHi);
            }
            const float acc = (lane < 32) ? aLo : aHi;
            ml2 = lif_update(ml2, acc + b2);
        }
        const uint64_t s2 = __ballot(ml2 > 1.0f);
        const uint32_t s2Lo = (uint32_t)s2, s2Hi = (uint32_t)(s2 >> 32);

        // ---- c (bits 8-10 of inLo, uniform) ----
        {
            float acc = 0.f;
#pragma unroll
            for (int k = 0; k < 3; ++k)
                acc = fmaf(wcr[k], ubit(inLo, 8 + k), acc);
            mc = lif_update(mc, acc + bcr);
        }
        const uint32_t sc = (uint32_t)__ballot((lane < 16) && (mc > 1.0f));

        // ---- f: 80 MACs, register weights, uniform masks ----
        {
            float acc = 0.f;
#pragma unroll
            for (int k = 0; k < 32; ++k)
                acc = fmaf(wf[k],      ubit(s2Lo, k), acc);
#pragma unroll
            for (int k = 0; k < 32; ++k)
                acc = fmaf(wf[32 + k], ubit(s2Hi, k), acc);
#pragma unroll
            for (int k = 0; k < 16; ++k)
                acc = fmaf(wf[64 + k], ubit(sc, k), acc);
            mf = lif_update(mf, acc + bfr);
        }
        const uint64_t sf = __ballot(mf > 1.0f);
        const uint32_t sfLo = (uint32_t)sf, sfHi = (uint32_t)(sf >> 32);

        // ---- f2: 64 MACs, weights streamed from LDS as float4 ----
        {
            float acc = 0.f;
#pragma unroll
            for (int q = 0; q < 16; ++q) {
                const float4 wq = wf2q[q];
                const uint32_t mm = (q < 8) ? sfLo : sfHi;
                const int kb = (q & 7) * 4;
                acc = fmaf(wq.x, ubit(mm, kb + 0), acc);
                acc = fmaf(wq.y, ubit(mm, kb + 1), acc);
                acc = fmaf(wq.z, ubit(mm, kb + 2), acc);
                acc = fmaf(wq.w, ubit(mm, kb + 3), acc);
            }
            mf2 = lif_update(mf2, acc + bf2r);
        }
        const uint64_t sf2 = __ballot((lane < 48) && (mf2 > 1.0f));
        const uint32_t f2Lo = (uint32_t)sf2, f2Hi = (uint32_t)(sf2 >> 32);

        // ---- o: 48 MACs, LDS float4 weights + uniform masks ----
        {
            float acc = 0.f;
#pragma unroll
            for (int q = 0; q < 12; ++q) {
                const float4 wq = wo4[q];
                const uint32_t mm = (q < 8) ? f2Lo : f2Hi;
                const int kb = (q < 8) ? (q * 4) : ((q - 8) * 4);
                acc = fmaf(wq.x, ubit(mm, kb + 0), acc);
                acc = fmaf(wq.y, ubit(mm, kb + 1), acc);
                acc = fmaf(wq.z, ubit(mm, kb + 2), acc);
                acc = fmaf(wq.w, ubit(mm, kb + 3), acc);
            }
            mo = lif_update(mo, acc + bor);
            if ((lane & 15) == 0)
                out[base * 4 + n_o] = (mo > 1.0f) ? 1.0f : 0.0f;
        }
    }
}

extern "C" void kernel_launch(void* const* d_in, const int* in_sizes, int n_in,
                              void* d_out, int out_size, void* d_ws, size_t ws_size,
                              hipStream_t stream) {
    const float* left  = (const float*)d_in[0];
    const float* right = (const float*)d_in[1];
    const float* ctx   = (const float*)d_in[2];
    const float* Wl1   = (const float*)d_in[3];
    const float* bl1   = (const float*)d_in[4];
    const float* Wl2   = (const float*)d_in[5];
    const float* bl2   = (const float*)d_in[6];
    const float* Wr1   = (const float*)d_in[7];
    const float* br1   = (const float*)d_in[8];
    const float* Wr2   = (const float*)d_in[9];
    const float* br2   = (const float*)d_in[10];
    const float* Wc    = (const float*)d_in[11];
    const float* bc    = (const float*)d_in[12];
    const float* Wf    = (const float*)d_in[13];
    const float* bf    = (const float*)d_in[14];
    const float* Wf2   = (const float*)d_in[15];
    const float* bf2   = (const float*)d_in[16];
    const float* Wo    = (const float*)d_in[17];
    const float* bo    = (const float*)d_in[18];
    float* out = (float*)d_out;

    hipLaunchKernelGGL(snn_kernel, dim3(BATCH / 4), dim3(256), 0, stream,
                       left, right, ctx, Wl1, bl1, Wl2, bl2, Wr1, br1, Wr2, br2,
                       Wc, bc, Wf, bf, Wf2, bf2, Wo, bo, out);
}

// Round 21
// 1949.166 us; speedup vs baseline: 4.3297x; 4.3297x over previous
//
#include <hip/hip_runtime.h>
#include <stdint.h>

#define T_STEPS 256
#define BATCH   8192

// Reference semantics (proven, rounds 16/17/19, absmax=0):
//   cur  = sum_k fmaf(w[k], s_k, acc) ascending, single acc; + bias at end
//   mem' = fmaf(0.95, mem, cur) - reset    (reset from OLD mem, {0,1})
//   spike = mem' > 1.0
__device__ __forceinline__ float lif_update(float mem, float cur) {
#pragma clang fp contract(off)
    float reset = (mem > 1.0f) ? 1.0f : 0.0f;
    return fmaf(0.95f, mem, cur) - reset;
}

__device__ __forceinline__ float ubit(uint32_t mask, int k) {
    return (float)((mask >> k) & 1u);
}

#define F2T_STRIDE 49   // float2 per k2-row: 48 lanes + 1 pad

__global__ __launch_bounds__(256, 2)
void snn_kernel(const float* __restrict__ left, const float* __restrict__ right,
                const float* __restrict__ ctx,
                const float* __restrict__ Wl1, const float* __restrict__ bl1,
                const float* __restrict__ Wl2, const float* __restrict__ bl2,
                const float* __restrict__ Wr1, const float* __restrict__ br1,
                const float* __restrict__ Wr2, const float* __restrict__ br2,
                const float* __restrict__ Wc,  const float* __restrict__ bc,
                const float* __restrict__ Wf,  const float* __restrict__ bf,
                const float* __restrict__ Wf2, const float* __restrict__ bf2,
                const float* __restrict__ Wo,  const float* __restrict__ bo,
                float* __restrict__ out)
{
    const int lane = threadIdx.x & 63;
    const int w_id = threadIdx.x >> 6;
    const int b    = blockIdx.x * 4 + w_id;

    const int j32 = lane & 31;
    const int jc  = lane & 15;
    const int jf2 = (lane < 48) ? lane : 47;   // lanes 48-63 shadow row
    const int n_o = lane >> 4;

    // ---- LDS: per-wave spike-float regions + transposed f2 weights + Wo ----
    __shared__ __align__(16) float  spk_all[4][256];
    __shared__ __align__(16) float2 wf2t[32 * F2T_STRIDE];   // [k2][n]
    __shared__ __align__(16) float  wo_s[4 * 48];

    for (int i = threadIdx.x; i < 32 * 48; i += 256) {
        const int k2 = i / 48, n = i - k2 * 48;
        wf2t[k2 * F2T_STRIDE + n] =
            make_float2(Wf2[n * 64 + 2 * k2], Wf2[n * 64 + 2 * k2 + 1]);
    }
    for (int i = threadIdx.x; i < 4 * 48; i += 256) wo_s[i] = Wo[i];
    __syncthreads();

    float* spk  = spk_all[w_id];
    float* l1f  = spk;          // 64 floats: l1/r1 spikes (lane j -> slot j)
    float* l2cf = spk + 64;     // 80 floats: [l2 0-31 | r2 32-63 | c 64-79]
    float* ff   = spk + 144;    // 64 floats: f spikes
    float* f2f  = spk + 208;    // 48 floats: f2 spikes

    // ---- register weights: 121 floats/lane ----
    float w1[6], w2[32], wcr[3], wf[80];
    const float* W1row = (lane < 32) ? (Wl1 + lane * 6)  : (Wr1 + j32 * 6);
    const float* W2row = (lane < 32) ? (Wl2 + lane * 32) : (Wr2 + j32 * 32);
    const float  b1    = (lane < 32) ? bl1[lane] : br1[j32];
    const float  b2    = (lane < 32) ? bl2[lane] : br2[j32];
#pragma unroll
    for (int k = 0; k < 6;  ++k) w1[k]  = W1row[k];
#pragma unroll
    for (int k = 0; k < 32; ++k) w2[k]  = W2row[k];
#pragma unroll
    for (int k = 0; k < 3;  ++k) wcr[k] = Wc[jc * 3 + k];
    const float bcr  = bc[jc];
#pragma unroll
    for (int k = 0; k < 80; ++k) wf[k]  = Wf[lane * 80 + k];
    const float bfr  = bf[lane];
    const float bf2r = bf2[jf2];
    const float bor  = bo[n_o];
    const float2* wrow2 = &wf2t[jf2];   // row jf2, stride F2T_STRIDE float2

    // ---- membrane state ----
    float ml1 = 0.f, ml2 = 0.f, mc = 0.f, mf = 0.f, mf2 = 0.f, mo = 0.f;

    for (int t = 0; t < T_STEPS; ++t) {
        const size_t base = (size_t)t * BATCH + b;

        // ---- inputs -> one ballot (for l1 and c masks only) ----
        float vin = 0.f;
        if (lane < 6)                     vin = left [base * 6 + lane];
        else if (lane >= 32 && lane < 38) vin = right[base * 6 + (lane - 32)];
        else if (lane >= 8 && lane < 11)  vin = ctx  [base * 3 + (lane - 8)];
        const uint64_t in_mask = __ballot(vin > 0.5f);
        const uint32_t inLo = (uint32_t)in_mask;
        const uint32_t inHi = (uint32_t)(in_mask >> 32);

        // ---- l1/r1: mask decode (6 MACs) ----
        {
            float aLo = 0.f, aHi = 0.f;
#pragma unroll
            for (int k = 0; k < 6; ++k) {
                aLo = fmaf(w1[k], ubit(inLo, k), aLo);
                aHi = fmaf(w1[k], ubit(inHi, k), aHi);
            }
            const float acc = (lane < 32) ? aLo : aHi;
            ml1 = lif_update(ml1, acc + b1);
        }
        l1f[lane] = (ml1 > 1.0f) ? 1.0f : 0.0f;

        // ---- l2/r2: spikes from LDS (8x b128), weights in regs ----
        {
            const float4* sl = reinterpret_cast<const float4*>(l1f + ((lane < 32) ? 0 : 32));
            float acc = 0.f;
#pragma unroll
            for (int q = 0; q < 8; ++q) {
                const float4 s4 = sl[q];
                acc = fmaf(w2[4 * q + 0], s4.x, acc);
                acc = fmaf(w2[4 * q + 1], s4.y, acc);
                acc = fmaf(w2[4 * q + 2], s4.z, acc);
                acc = fmaf(w2[4 * q + 3], s4.w, acc);
            }
            ml2 = lif_update(ml2, acc + b2);
        }
        l2cf[lane] = (ml2 > 1.0f) ? 1.0f : 0.0f;

        // ---- c: mask decode (3 MACs, bits 8-10 of inLo, all lanes shadow) ----
        {
            float acc = 0.f;
#pragma unroll
            for (int k = 0; k < 3; ++k)
                acc = fmaf(wcr[k], ubit(inLo, 8 + k), acc);
            mc = lif_update(mc, acc + bcr);
        }
        if (lane < 16) l2cf[64 + lane] = (mc > 1.0f) ? 1.0f : 0.0f;

        // ---- f: 80 MACs, spikes via 20x uniform b128, weights in regs ----
        {
            const float4* sl = reinterpret_cast<const float4*>(l2cf);
            float acc = 0.f;
#pragma unroll
            for (int q = 0; q < 20; ++q) {
                const float4 s4 = sl[q];
                acc = fmaf(wf[4 * q + 0], s4.x, acc);
                acc = fmaf(wf[4 * q + 1], s4.y, acc);
                acc = fmaf(wf[4 * q + 2], s4.z, acc);
                acc = fmaf(wf[4 * q + 3], s4.w, acc);
            }
            mf = lif_update(mf, acc + bfr);
        }
        ff[lane] = (mf > 1.0f) ? 1.0f : 0.0f;

        // ---- f2: 64 MACs, weights from LDS (transposed, per-lane row),
        //      spikes via uniform b64 pairs ----
        {
            const float2* sp = reinterpret_cast<const float2*>(ff);
            float acc = 0.f;
#pragma unroll
            for (int k2 = 0; k2 < 32; ++k2) {
                const float2 wv = wrow2[k2 * F2T_STRIDE];
                const float2 sv = sp[k2];
                acc = fmaf(wv.x, sv.x, acc);
                acc = fmaf(wv.y, sv.y, acc);
            }
            mf2 = lif_update(mf2, acc + bf2r);
        }
        if (lane < 48) f2f[lane] = (mf2 > 1.0f) ? 1.0f : 0.0f;

        // ---- o: 48 MACs, wo from LDS float4, spikes via uniform b128 ----
        {
            const float4* sl  = reinterpret_cast<const float4*>(f2f);
            const float4* wo4 = reinterpret_cast<const float4*>(&wo_s[n_o * 48]);
            float acc = 0.f;
#pragma unroll
            for (int q = 0; q < 12; ++q) {
                const float4 w4 = wo4[q];
                const float4 s4 = sl[q];
                acc = fmaf(w4.x, s4.x, acc);
                acc = fmaf(w4.y, s4.y, acc);
                acc = fmaf(w4.z, s4.z, acc);
                acc = fmaf(w4.w, s4.w, acc);
            }
            mo = lif_update(mo, acc + bor);
            if ((lane & 15) == 0)
                out[base * 4 + n_o] = (mo > 1.0f) ? 1.0f : 0.0f;
        }
    }
}

extern "C" void kernel_launch(void* const* d_in, const int* in_sizes, int n_in,
                              void* d_out, int out_size, void* d_ws, size_t ws_size,
                              hipStream_t stream) {
    const float* left  = (const float*)d_in[0];
    const float* right = (const float*)d_in[1];
    const float* ctx   = (const float*)d_in[2];
    const float* Wl1   = (const float*)d_in[3];
    const float* bl1   = (const float*)d_in[4];
    const float* Wl2   = (const float*)d_in[5];
    const float* bl2   = (const float*)d_in[6];
    const float* Wr1   = (const float*)d_in[7];
    const float* br1   = (const float*)d_in[8];
    const float* Wr2   = (const float*)d_in[9];
    const float* br2   = (const float*)d_in[10];
    const float* Wc    = (const float*)d_in[11];
    const float* bc    = (const float*)d_in[12];
    const float* Wf    = (const float*)d_in[13];
    const float* bf    = (const float*)d_in[14];
    const float* Wf2   = (const float*)d_in[15];
    const float* bf2   = (const float*)d_in[16];
    const float* Wo    = (const float*)d_in[17];
    const float* bo    = (const float*)d_in[18];
    float* out = (float*)d_out;

    hipLaunchKernelGGL(snn_kernel, dim3(BATCH / 4), dim3(256), 0, stream,
                       left, right, ctx, Wl1, bl1, Wl2, bl2, Wr1, br1, Wr2, br2,
                       Wc, bc, Wf, bf, Wf2, bf2, Wo, bo, out);
}